// Round 2
// baseline (5863.082 us; speedup 1.0000x reference)
//
#include <hip/hip_runtime.h>
#include <hip/hip_bf16.h>

// GCN: h1 = relu(Agg(x@W1)+b1); h2 = relu(Agg(h1@W2)+b2); out = mean(h2)@Wc + bc
// Agg uses sym-normalized adjacency with self loops: dinv[i]=rsqrt(deg_in[i]+1).
// All float tensors are fp32 (per reference dtypes); edge_index arrives as int32.

#define FEAT 128

// ---- degree count: cnt[dst]++ over E edges ----
__global__ __launch_bounds__(256) void count_kernel(const int* __restrict__ dst,
                                                    int* __restrict__ cnt, int nE) {
    int e = blockIdx.x * 256 + threadIdx.x;
    if (e < nE) atomicAdd(&cnt[dst[e]], 1);
}

// ---- dinv[i] = rsqrt(cnt[i] + 1)  (+1 = self loop) ----
__global__ __launch_bounds__(256) void dinv_kernel(const int* __restrict__ cnt,
                                                   float* __restrict__ dinv, int n) {
    int i = blockIdx.x * 256 + threadIdx.x;
    if (i < n) dinv[i] = rsqrtf((float)(cnt[i] + 1));
}

// ---- GEMM: out[N][128] = X[N][128] @ W[128][128], fp32 accumulate ----
// W fully staged in LDS (64KB fp32). 64 rows/block, each thread: 1 row x 32 cols.
__global__ __launch_bounds__(256) void gemm_node(const float* __restrict__ X,
                                                 const float* __restrict__ W,
                                                 float* __restrict__ out, int n) {
    __shared__ float Ws[FEAT * FEAT];
    for (int i = threadIdx.x; i < FEAT * FEAT / 4; i += 256)
        ((float4*)Ws)[i] = ((const float4*)W)[i];
    __syncthreads();

    int row = blockIdx.x * 64 + (threadIdx.x >> 2);
    int cb  = (threadIdx.x & 3) * 32;
    if (row >= n) return;

    float acc[32];
#pragma unroll
    for (int j = 0; j < 32; j++) acc[j] = 0.0f;

    const float* xr = X + (size_t)row * FEAT;
    for (int k = 0; k < FEAT; k += 4) {
        float4 a4 = *(const float4*)(xr + k);
#pragma unroll
        for (int kk = 0; kk < 4; kk++) {
            float a = (&a4.x)[kk];
            const float* wr = &Ws[(k + kk) * FEAT + cb];
#pragma unroll
            for (int j = 0; j < 32; j++) acc[j] += a * wr[j];
        }
    }
    float* o = out + (size_t)row * FEAT + cb;
#pragma unroll
    for (int j = 0; j < 32; j += 4)
        *(float4*)(o + j) = make_float4(acc[j], acc[j + 1], acc[j + 2], acc[j + 3]);
}

// ---- init aggregate with self-loop term: outb[i] = h[i] * dinv[i]^2 ----
__global__ __launch_bounds__(256) void init_kernel(const float* __restrict__ h,
                                                   const float* __restrict__ dinv,
                                                   float* __restrict__ outb, int n) {
    long long gid = (long long)blockIdx.x * 256 + threadIdx.x;  // n*32 threads
    long long i = gid >> 5;
    if (i >= n) return;
    int q = (int)(gid & 31) * 4;
    float d = dinv[i];
    float s = d * d;
    float4 hv = *(const float4*)(h + i * FEAT + q);
    float4 r;
    r.x = hv.x * s; r.y = hv.y * s; r.z = hv.z * s; r.w = hv.w * s;
    *(float4*)(outb + i * FEAT + q) = r;
}

// ---- edge scatter: outb[dst] += h[src] * (dinv[src]*dinv[dst]) ----
__global__ __launch_bounds__(256) void agg_kernel(const int* __restrict__ src,
                                                  const int* __restrict__ dst,
                                                  const float* __restrict__ dinv,
                                                  const float* __restrict__ h,
                                                  float* __restrict__ outb, int nE) {
    long long gid = (long long)blockIdx.x * 256 + threadIdx.x;  // nE*32 threads
    long long e = gid >> 5;
    if (e >= nE) return;
    int q = (int)(gid & 31) * 4;
    int s = src[e], d = dst[e];
    float nrm = dinv[s] * dinv[d];
    float4 hv = *(const float4*)(h + (size_t)s * FEAT + q);
    float* o = outb + (size_t)d * FEAT + q;
    atomicAdd(o + 0, hv.x * nrm);
    atomicAdd(o + 1, hv.y * nrm);
    atomicAdd(o + 2, hv.z * nrm);
    atomicAdd(o + 3, hv.w * nrm);
}

// ---- in-place bias + relu ----
__global__ __launch_bounds__(256) void bias_relu_kernel(float* __restrict__ a,
                                                        const float* __restrict__ b,
                                                        long long n4) {
    long long gid = (long long)blockIdx.x * 256 + threadIdx.x;  // n*32 threads
    if (gid >= n4) return;
    int q = (int)(gid & 31) * 4;
    float4 v = ((float4*)a)[gid];
    v.x = fmaxf(v.x + b[q + 0], 0.0f);
    v.y = fmaxf(v.y + b[q + 1], 0.0f);
    v.z = fmaxf(v.z + b[q + 2], 0.0f);
    v.w = fmaxf(v.w + b[q + 3], 0.0f);
    ((float4*)a)[gid] = v;
}

// ---- mean pool stage 1: pooled[f] += sum over strided rows ----
__global__ __launch_bounds__(256) void pool_kernel(const float* __restrict__ a,
                                                   float* __restrict__ pooled, int n) {
    int tid = blockIdx.x * 256 + threadIdx.x;  // 256 blocks -> 65536 threads
    int f = tid & 127;
    int i0 = tid >> 7;  // 0..511
    float s = 0.0f;
    for (int i = i0; i < n; i += 512) s += a[(size_t)i * FEAT + f];
    atomicAdd(&pooled[f], s);
}

// ---- final: out[c] = (pooled/N) . Wc[:,c] + bc[c] ----
__global__ __launch_bounds__(128) void final_kernel(const float* __restrict__ pooled,
                                                    const float* __restrict__ Wc,
                                                    const float* __restrict__ bc,
                                                    float* __restrict__ out,
                                                    int n, int C) {
    __shared__ float p[FEAT];
    int t = threadIdx.x;
    p[t] = pooled[t] * (1.0f / (float)n);
    __syncthreads();
    if (t < C) {
        float acc = bc[t];
        for (int h = 0; h < FEAT; h++)
            acc += p[h] * Wc[h * C + t];
        out[t] = acc;
    }
}

extern "C" void kernel_launch(void* const* d_in, const int* in_sizes, int n_in,
                              void* d_out, int out_size, void* d_ws, size_t ws_size,
                              hipStream_t stream) {
    const float* x  = (const float*)d_in[0];
    const int*   ei = (const int*)d_in[1];
    const float* W1 = (const float*)d_in[2];
    const float* b1 = (const float*)d_in[3];
    const float* W2 = (const float*)d_in[4];
    const float* b2 = (const float*)d_in[5];
    const float* Wc = (const float*)d_in[6];
    const float* bc = (const float*)d_in[7];

    const int N = in_sizes[0] / FEAT;      // 100000
    const int E = in_sizes[1] / 2;         // 1600000
    const int C = out_size;                // 32
    const int* srcI = ei;
    const int* dstI = ei + E;

    // workspace carve (256B aligned)
    auto align256 = [](size_t v) { return (v + 255) & ~(size_t)255; };
    char* w = (char*)d_ws;
    int*   cnt    = (int*)w;    w += align256((size_t)N * 4);
    float* dinv   = (float*)w;  w += align256((size_t)N * 4);
    float* bufH   = (float*)w;  w += align256((size_t)N * FEAT * 4);
    float* bufA   = (float*)w;  w += align256((size_t)N * FEAT * 4);
    float* pooled = (float*)w;  w += align256((size_t)FEAT * 4);

    hipMemsetAsync(cnt, 0, (size_t)N * 4, stream);
    hipMemsetAsync(pooled, 0, (size_t)FEAT * 4, stream);

    // degrees
    count_kernel<<<(E + 255) / 256, 256, 0, stream>>>(dstI, cnt, E);
    dinv_kernel<<<(N + 255) / 256, 256, 0, stream>>>(cnt, dinv, N);

    const long long n32 = (long long)N * 32;            // threads for per-node f4 kernels
    const int gN32 = (int)((n32 + 255) / 256);
    const long long e32 = (long long)E * 32;
    const int gE32 = (int)((e32 + 255) / 256);

    // ---- layer 1 ----
    gemm_node<<<(N + 63) / 64, 256, 0, stream>>>(x, W1, bufH, N);
    init_kernel<<<gN32, 256, 0, stream>>>(bufH, dinv, bufA, N);
    agg_kernel<<<gE32, 256, 0, stream>>>(srcI, dstI, dinv, bufH, bufA, E);
    bias_relu_kernel<<<gN32, 256, 0, stream>>>(bufA, b1, n32);

    // ---- layer 2 ----
    gemm_node<<<(N + 63) / 64, 256, 0, stream>>>(bufA, W2, bufH, N);
    init_kernel<<<gN32, 256, 0, stream>>>(bufH, dinv, bufA, N);
    agg_kernel<<<gE32, 256, 0, stream>>>(srcI, dstI, dinv, bufH, bufA, E);
    bias_relu_kernel<<<gN32, 256, 0, stream>>>(bufA, b2, n32);

    // ---- pool + classifier ----
    pool_kernel<<<256, 256, 0, stream>>>(bufA, pooled, N);
    final_kernel<<<1, 128, 0, stream>>>(pooled, Wc, bc, (float*)d_out, N, C);
}

// Round 3
// 838.572 us; speedup vs baseline: 6.9917x; 6.9917x over previous
//
#include <hip/hip_runtime.h>
#include <hip/hip_bf16.h>

// GCN: h1 = relu(Agg(x@W1)+b1); h2 = relu(Agg(h1@W2)+b2); out = mean(h2)@Wc + bc
// Agg via CSR gather (no fp32 atomics):
//   g = (X@W) * dinv[row]   (fused GEMM epilogue)
//   out[d] = relu( dinv[d] * (g[d] + sum_{e: dst=d} g[src_e]) + b )
// since norm(s,d) = dinv[s]*dinv[d] factors: dinv[d] * (dinv[s]*h[s]).

#define FEAT 128

// ---- degree count: cnt[dst]++ over E edges ----
__global__ __launch_bounds__(256) void count_kernel(const int* __restrict__ dst,
                                                    int* __restrict__ cnt, int nE) {
    int e = blockIdx.x * 256 + threadIdx.x;
    if (e < nE) atomicAdd(&cnt[dst[e]], 1);
}

// ---- dinv[i] = rsqrt(cnt[i] + 1)  (+1 = self loop) ----
__global__ __launch_bounds__(256) void dinv_kernel(const int* __restrict__ cnt,
                                                   float* __restrict__ dinv, int n) {
    int i = blockIdx.x * 256 + threadIdx.x;
    if (i < n) dinv[i] = rsqrtf((float)(cnt[i] + 1));
}

// ---- scan K1: per-block (1024 elems) sums ----
__global__ __launch_bounds__(256) void scan_bsum(const int* __restrict__ cnt,
                                                 int* __restrict__ bsum, int n) {
    __shared__ int red[256];
    int b = blockIdx.x, t = threadIdx.x;
    int base = b * 1024 + t * 4;
    int s = 0;
#pragma unroll
    for (int k = 0; k < 4; k++) {
        int i = base + k;
        if (i < n) s += cnt[i];
    }
    red[t] = s;
    __syncthreads();
    for (int off = 128; off > 0; off >>= 1) {
        if (t < off) red[t] += red[t + off];
        __syncthreads();
    }
    if (t == 0) bsum[b] = red[0];
}

// ---- scan K2: exclusive scan of block sums (single thread; nb ~ 98) ----
__global__ void scan_boff(const int* __restrict__ bsum, int* __restrict__ boff, int nb) {
    int run = 0;
    for (int i = 0; i < nb; i++) { boff[i] = run; run += bsum[i]; }
}

// ---- scan K3: per-block exclusive scan -> cursor[i] = global exclusive prefix ----
__global__ __launch_bounds__(256) void scan_write(const int* __restrict__ cnt,
                                                  const int* __restrict__ boff,
                                                  int* __restrict__ cursor, int n) {
    __shared__ int sc[256];
    int b = blockIdx.x, t = threadIdx.x;
    int base = b * 1024 + t * 4;
    int v[4];
    int s = 0;
#pragma unroll
    for (int k = 0; k < 4; k++) {
        int i = base + k;
        v[k] = (i < n) ? cnt[i] : 0;
        s += v[k];
    }
    sc[t] = s;
    __syncthreads();
    // Hillis-Steele inclusive scan over thread sums
    for (int off = 1; off < 256; off <<= 1) {
        int add = (t >= off) ? sc[t - off] : 0;
        __syncthreads();
        sc[t] += add;
        __syncthreads();
    }
    int excl = boff[b] + sc[t] - s;  // exclusive prefix for this thread's chunk
#pragma unroll
    for (int k = 0; k < 4; k++) {
        int i = base + k;
        if (i < n) cursor[i] = excl;
        excl += v[k];
    }
}

// ---- scatter edges into CSR buckets (cursor advances to bucket end) ----
__global__ __launch_bounds__(256) void csr_scatter(const int* __restrict__ src,
                                                   const int* __restrict__ dst,
                                                   int* __restrict__ cursor,
                                                   int* __restrict__ csr_src, int nE) {
    int e = blockIdx.x * 256 + threadIdx.x;
    if (e >= nE) return;
    int pos = atomicAdd(&cursor[dst[e]], 1);
    csr_src[pos] = src[e];
}

// ---- GEMM: out[N][128] = (X[N][128] @ W[128][128]) * dinv[row] ----
__global__ __launch_bounds__(256) void gemm_node(const float* __restrict__ X,
                                                 const float* __restrict__ W,
                                                 const float* __restrict__ dinv,
                                                 float* __restrict__ out, int n) {
    __shared__ float Ws[FEAT * FEAT];
    for (int i = threadIdx.x; i < FEAT * FEAT / 4; i += 256)
        ((float4*)Ws)[i] = ((const float4*)W)[i];
    __syncthreads();

    int row = blockIdx.x * 64 + (threadIdx.x >> 2);
    int cb  = (threadIdx.x & 3) * 32;
    if (row >= n) return;

    float acc[32];
#pragma unroll
    for (int j = 0; j < 32; j++) acc[j] = 0.0f;

    const float* xr = X + (size_t)row * FEAT;
    for (int k = 0; k < FEAT; k += 4) {
        float4 a4 = *(const float4*)(xr + k);
#pragma unroll
        for (int kk = 0; kk < 4; kk++) {
            float a = (&a4.x)[kk];
            const float* wr = &Ws[(k + kk) * FEAT + cb];
#pragma unroll
            for (int j = 0; j < 32; j++) acc[j] += a * wr[j];
        }
    }
    float dv = dinv[row];
    float* o = out + (size_t)row * FEAT + cb;
#pragma unroll
    for (int j = 0; j < 32; j += 4)
        *(float4*)(o + j) = make_float4(acc[j] * dv, acc[j + 1] * dv,
                                        acc[j + 2] * dv, acc[j + 3] * dv);
}

// ---- fused CSR aggregate + bias + relu. One wave per node, float2 per lane ----
__global__ __launch_bounds__(256) void agg_csr(const int* __restrict__ cursor,
                                               const int* __restrict__ cnt,
                                               const int* __restrict__ csr_src,
                                               const float* __restrict__ g,
                                               const float* __restrict__ dinv,
                                               const float* __restrict__ bias,
                                               float* __restrict__ outb, int n) {
    int node = blockIdx.x * 4 + (threadIdx.x >> 6);
    if (node >= n) return;
    int lane = threadIdx.x & 63;
    const float2* g2 = (const float2*)g;

    int num = cnt[node];
    int end = cursor[node];       // after scatter, cursor = bucket end
    int beg = end - num;

    float2 a0 = g2[(size_t)node * 64 + lane];  // self-loop term g[d]
    float2 a1 = make_float2(0.f, 0.f);
    float2 a2 = make_float2(0.f, 0.f);
    float2 a3 = make_float2(0.f, 0.f);

    int j = beg;
    for (; j + 3 < end; j += 4) {
        int s0 = csr_src[j + 0];
        int s1 = csr_src[j + 1];
        int s2 = csr_src[j + 2];
        int s3 = csr_src[j + 3];
        float2 v0 = g2[(size_t)s0 * 64 + lane];
        float2 v1 = g2[(size_t)s1 * 64 + lane];
        float2 v2 = g2[(size_t)s2 * 64 + lane];
        float2 v3 = g2[(size_t)s3 * 64 + lane];
        a0.x += v0.x; a0.y += v0.y;
        a1.x += v1.x; a1.y += v1.y;
        a2.x += v2.x; a2.y += v2.y;
        a3.x += v3.x; a3.y += v3.y;
    }
    for (; j < end; j++) {
        int s0 = csr_src[j];
        float2 v0 = g2[(size_t)s0 * 64 + lane];
        a0.x += v0.x; a0.y += v0.y;
    }

    float dv = dinv[node];
    float2 bv = ((const float2*)bias)[lane];
    float sx = a0.x + a1.x + a2.x + a3.x;
    float sy = a0.y + a1.y + a2.y + a3.y;
    float2 r;
    r.x = fmaxf(sx * dv + bv.x, 0.0f);
    r.y = fmaxf(sy * dv + bv.y, 0.0f);
    ((float2*)outb)[(size_t)node * 64 + lane] = r;
}

// ---- mean pool stage 1 ----
__global__ __launch_bounds__(256) void pool_kernel(const float* __restrict__ a,
                                                   float* __restrict__ pooled, int n) {
    int tid = blockIdx.x * 256 + threadIdx.x;  // 256 blocks -> 65536 threads
    int f = tid & 127;
    int i0 = tid >> 7;  // 0..511
    float s = 0.0f;
    for (int i = i0; i < n; i += 512) s += a[(size_t)i * FEAT + f];
    atomicAdd(&pooled[f], s);
}

// ---- final: out[c] = (pooled/N) . Wc[:,c] + bc[c] ----
__global__ __launch_bounds__(128) void final_kernel(const float* __restrict__ pooled,
                                                    const float* __restrict__ Wc,
                                                    const float* __restrict__ bc,
                                                    float* __restrict__ out,
                                                    int n, int C) {
    __shared__ float p[FEAT];
    int t = threadIdx.x;
    p[t] = pooled[t] * (1.0f / (float)n);
    __syncthreads();
    if (t < C) {
        float acc = bc[t];
        for (int h = 0; h < FEAT; h++)
            acc += p[h] * Wc[h * C + t];
        out[t] = acc;
    }
}

extern "C" void kernel_launch(void* const* d_in, const int* in_sizes, int n_in,
                              void* d_out, int out_size, void* d_ws, size_t ws_size,
                              hipStream_t stream) {
    const float* x  = (const float*)d_in[0];
    const int*   ei = (const int*)d_in[1];
    const float* W1 = (const float*)d_in[2];
    const float* b1 = (const float*)d_in[3];
    const float* W2 = (const float*)d_in[4];
    const float* b2 = (const float*)d_in[5];
    const float* Wc = (const float*)d_in[6];
    const float* bc = (const float*)d_in[7];

    const int N = in_sizes[0] / FEAT;      // 100000
    const int E = in_sizes[1] / 2;         // 1600000
    const int C = out_size;                // 32
    const int* srcI = ei;
    const int* dstI = ei + E;
    const int NB = (N + 1023) / 1024;      // scan blocks

    // workspace carve (256B aligned)
    auto align256 = [](size_t v) { return (v + 255) & ~(size_t)255; };
    char* w = (char*)d_ws;
    int*   cnt     = (int*)w;    w += align256((size_t)N * 4);
    float* dinv    = (float*)w;  w += align256((size_t)N * 4);
    int*   cursor  = (int*)w;    w += align256((size_t)N * 4);
    int*   csr_src = (int*)w;    w += align256((size_t)E * 4);
    int*   bsum    = (int*)w;    w += align256((size_t)NB * 4);
    int*   boff    = (int*)w;    w += align256((size_t)NB * 4);
    float* bufH    = (float*)w;  w += align256((size_t)N * FEAT * 4);
    float* bufA    = (float*)w;  w += align256((size_t)N * FEAT * 4);
    float* pooled  = (float*)w;  w += align256((size_t)FEAT * 4);

    hipMemsetAsync(cnt, 0, (size_t)N * 4, stream);
    hipMemsetAsync(pooled, 0, (size_t)FEAT * 4, stream);

    // degrees + dinv
    count_kernel<<<(E + 255) / 256, 256, 0, stream>>>(dstI, cnt, E);
    dinv_kernel<<<(N + 255) / 256, 256, 0, stream>>>(cnt, dinv, N);

    // CSR build (shared by both layers)
    scan_bsum<<<NB, 256, 0, stream>>>(cnt, bsum, N);
    scan_boff<<<1, 1, 0, stream>>>(bsum, boff, NB);
    scan_write<<<NB, 256, 0, stream>>>(cnt, boff, cursor, N);
    csr_scatter<<<(E + 255) / 256, 256, 0, stream>>>(srcI, dstI, cursor, csr_src, E);

    const int gAgg = (N + 3) / 4;

    // ---- layer 1 ----
    gemm_node<<<(N + 63) / 64, 256, 0, stream>>>(x, W1, dinv, bufH, N);
    agg_csr<<<gAgg, 256, 0, stream>>>(cursor, cnt, csr_src, bufH, dinv, b1, bufA, N);

    // ---- layer 2 ----
    gemm_node<<<(N + 63) / 64, 256, 0, stream>>>(bufA, W2, dinv, bufH, N);
    agg_csr<<<gAgg, 256, 0, stream>>>(cursor, cnt, csr_src, bufH, dinv, b2, bufA, N);

    // ---- pool + classifier ----
    pool_kernel<<<256, 256, 0, stream>>>(bufA, pooled, N);
    final_kernel<<<1, 128, 0, stream>>>(pooled, Wc, bc, (float*)d_out, N, C);
}

// Round 4
// 722.741 us; speedup vs baseline: 8.1123x; 1.1603x over previous
//
#include <hip/hip_runtime.h>
#include <hip/hip_bf16.h>

// GCN: h1 = relu(Agg(x@W1)+b1); h2 = relu(Agg(h1@W2)+b2); out = mean(h2)@Wc + bc
// Agg via CSR gather (no fp32 atomics):
//   g = (X@W) * dinv[row]   (fused GEMM epilogue)
//   out[d] = relu( dinv[d] * (g[d] + sum_{e: dst=d} g[src_e]) + b )

#define FEAT 128

// ---- degree count: cnt[dst]++ over E edges (int4 edge loads) ----
__global__ __launch_bounds__(256) void count_kernel(const int* __restrict__ dst,
                                                    int* __restrict__ cnt, int nE) {
    int e4 = blockIdx.x * 256 + threadIdx.x;
    int e = e4 * 4;
    if (e + 3 < nE) {
        int4 d4 = *(const int4*)(dst + e);
        atomicAdd(&cnt[d4.x], 1);
        atomicAdd(&cnt[d4.y], 1);
        atomicAdd(&cnt[d4.z], 1);
        atomicAdd(&cnt[d4.w], 1);
    } else {
        for (int k = e; k < nE; k++) atomicAdd(&cnt[dst[k]], 1);
    }
}

// ---- dinv[i] = rsqrt(cnt[i] + 1)  (+1 = self loop) ----
__global__ __launch_bounds__(256) void dinv_kernel(const int* __restrict__ cnt,
                                                   float* __restrict__ dinv, int n) {
    int i = blockIdx.x * 256 + threadIdx.x;
    if (i < n) dinv[i] = rsqrtf((float)(cnt[i] + 1));
}

// ---- scan K1: per-block (1024 elems) sums ----
__global__ __launch_bounds__(256) void scan_bsum(const int* __restrict__ cnt,
                                                 int* __restrict__ bsum, int n) {
    __shared__ int red[256];
    int b = blockIdx.x, t = threadIdx.x;
    int base = b * 1024 + t * 4;
    int s = 0;
#pragma unroll
    for (int k = 0; k < 4; k++) {
        int i = base + k;
        if (i < n) s += cnt[i];
    }
    red[t] = s;
    __syncthreads();
    for (int off = 128; off > 0; off >>= 1) {
        if (t < off) red[t] += red[t + off];
        __syncthreads();
    }
    if (t == 0) bsum[b] = red[0];
}

// ---- scan K2: exclusive scan of block sums (single thread; nb ~ 98) ----
__global__ void scan_boff(const int* __restrict__ bsum, int* __restrict__ boff, int nb) {
    int run = 0;
    for (int i = 0; i < nb; i++) { boff[i] = run; run += bsum[i]; }
}

// ---- scan K3: per-block exclusive scan -> cursor[i] = global exclusive prefix ----
__global__ __launch_bounds__(256) void scan_write(const int* __restrict__ cnt,
                                                  const int* __restrict__ boff,
                                                  int* __restrict__ cursor, int n) {
    __shared__ int sc[256];
    int b = blockIdx.x, t = threadIdx.x;
    int base = b * 1024 + t * 4;
    int v[4];
    int s = 0;
#pragma unroll
    for (int k = 0; k < 4; k++) {
        int i = base + k;
        v[k] = (i < n) ? cnt[i] : 0;
        s += v[k];
    }
    sc[t] = s;
    __syncthreads();
    for (int off = 1; off < 256; off <<= 1) {
        int add = (t >= off) ? sc[t - off] : 0;
        __syncthreads();
        sc[t] += add;
        __syncthreads();
    }
    int excl = boff[b] + sc[t] - s;
#pragma unroll
    for (int k = 0; k < 4; k++) {
        int i = base + k;
        if (i < n) cursor[i] = excl;
        excl += v[k];
    }
}

// ---- scatter edges into CSR buckets (cursor advances to bucket end) ----
__global__ __launch_bounds__(256) void csr_scatter(const int* __restrict__ src,
                                                   const int* __restrict__ dst,
                                                   int* __restrict__ cursor,
                                                   int* __restrict__ csr_src, int nE) {
    int e = blockIdx.x * 256 + threadIdx.x;
    if (e >= nE) return;
    int pos = atomicAdd(&cursor[dst[e]], 1);
    csr_src[pos] = src[e];
}

// ---- GEMM: out[N][128] = (X@W) * dinv[row]; 4 rows x 16 cols per thread ----
// W (64KB fp32) in LDS; per-thread W reads amortized over 4 rows.
__global__ __launch_bounds__(256) void gemm_node(const float* __restrict__ X,
                                                 const float* __restrict__ W,
                                                 const float* __restrict__ dinv,
                                                 float* __restrict__ out, int n) {
    __shared__ float Ws[FEAT * FEAT];
    for (int i = threadIdx.x; i < FEAT * FEAT / 4; i += 256)
        ((float4*)Ws)[i] = ((const float4*)W)[i];
    __syncthreads();

    int cg = threadIdx.x & 7;        // col group -> 16 cols
    int rs = threadIdx.x >> 3;       // row slot 0..31 -> 4 rows each
    int cb = cg * 16;
    int r0 = blockIdx.x * 128 + rs * 4;
    if (r0 >= n) return;
    bool full = (r0 + 3 < n);

    float acc[4][16];
#pragma unroll
    for (int rr = 0; rr < 4; rr++)
#pragma unroll
        for (int j = 0; j < 16; j++) acc[rr][j] = 0.0f;

    const float* x0 = X + (size_t)r0 * FEAT;

    for (int k = 0; k < FEAT; k += 4) {
        float4 a[4];
        if (full) {
#pragma unroll
            for (int rr = 0; rr < 4; rr++)
                a[rr] = *(const float4*)(x0 + (size_t)rr * FEAT + k);
        } else {
#pragma unroll
            for (int rr = 0; rr < 4; rr++)
                a[rr] = (r0 + rr < n) ? *(const float4*)(x0 + (size_t)rr * FEAT + k)
                                      : make_float4(0.f, 0.f, 0.f, 0.f);
        }
#pragma unroll
        for (int kk = 0; kk < 4; kk++) {
            const float* wr = &Ws[(k + kk) * FEAT + cb];
            float4 w0 = *(const float4*)(wr + 0);
            float4 w1 = *(const float4*)(wr + 4);
            float4 w2 = *(const float4*)(wr + 8);
            float4 w3 = *(const float4*)(wr + 12);
#pragma unroll
            for (int rr = 0; rr < 4; rr++) {
                float av = (&a[rr].x)[kk];
                acc[rr][0]  += av * w0.x; acc[rr][1]  += av * w0.y;
                acc[rr][2]  += av * w0.z; acc[rr][3]  += av * w0.w;
                acc[rr][4]  += av * w1.x; acc[rr][5]  += av * w1.y;
                acc[rr][6]  += av * w1.z; acc[rr][7]  += av * w1.w;
                acc[rr][8]  += av * w2.x; acc[rr][9]  += av * w2.y;
                acc[rr][10] += av * w2.z; acc[rr][11] += av * w2.w;
                acc[rr][12] += av * w3.x; acc[rr][13] += av * w3.y;
                acc[rr][14] += av * w3.z; acc[rr][15] += av * w3.w;
            }
        }
    }

#pragma unroll
    for (int rr = 0; rr < 4; rr++) {
        int r = r0 + rr;
        if (r >= n) break;
        float dv = dinv[r];
        float* o = out + (size_t)r * FEAT + cb;
#pragma unroll
        for (int j = 0; j < 16; j += 4)
            *(float4*)(o + j) = make_float4(acc[rr][j] * dv, acc[rr][j + 1] * dv,
                                            acc[rr][j + 2] * dv, acc[rr][j + 3] * dv);
    }
}

// ---- fused CSR aggregate + bias + relu. One wave per node, float2 per lane ----
__global__ __launch_bounds__(256) void agg_csr(const int* __restrict__ cursor,
                                               const int* __restrict__ cnt,
                                               const int* __restrict__ csr_src,
                                               const float* __restrict__ g,
                                               const float* __restrict__ dinv,
                                               const float* __restrict__ bias,
                                               float* __restrict__ outb, int n) {
    int node = blockIdx.x * 4 + (threadIdx.x >> 6);
    if (node >= n) return;
    int lane = threadIdx.x & 63;
    const float2* g2 = (const float2*)g;

    int num = cnt[node];
    int end = cursor[node];       // after scatter, cursor = bucket end
    int beg = end - num;

    float2 a0 = g2[(size_t)node * 64 + lane];  // self-loop term g[d]
    float2 a1 = make_float2(0.f, 0.f);
    float2 a2 = make_float2(0.f, 0.f);
    float2 a3 = make_float2(0.f, 0.f);

    int j = beg;
    for (; j + 7 < end; j += 8) {
        int s0 = csr_src[j + 0];
        int s1 = csr_src[j + 1];
        int s2 = csr_src[j + 2];
        int s3 = csr_src[j + 3];
        int s4 = csr_src[j + 4];
        int s5 = csr_src[j + 5];
        int s6 = csr_src[j + 6];
        int s7 = csr_src[j + 7];
        float2 v0 = g2[(size_t)s0 * 64 + lane];
        float2 v1 = g2[(size_t)s1 * 64 + lane];
        float2 v2 = g2[(size_t)s2 * 64 + lane];
        float2 v3 = g2[(size_t)s3 * 64 + lane];
        float2 v4 = g2[(size_t)s4 * 64 + lane];
        float2 v5 = g2[(size_t)s5 * 64 + lane];
        float2 v6 = g2[(size_t)s6 * 64 + lane];
        float2 v7 = g2[(size_t)s7 * 64 + lane];
        a0.x += v0.x; a0.y += v0.y;
        a1.x += v1.x; a1.y += v1.y;
        a2.x += v2.x; a2.y += v2.y;
        a3.x += v3.x; a3.y += v3.y;
        a0.x += v4.x; a0.y += v4.y;
        a1.x += v5.x; a1.y += v5.y;
        a2.x += v6.x; a2.y += v6.y;
        a3.x += v7.x; a3.y += v7.y;
    }
    for (; j + 3 < end; j += 4) {
        int s0 = csr_src[j + 0];
        int s1 = csr_src[j + 1];
        int s2 = csr_src[j + 2];
        int s3 = csr_src[j + 3];
        float2 v0 = g2[(size_t)s0 * 64 + lane];
        float2 v1 = g2[(size_t)s1 * 64 + lane];
        float2 v2 = g2[(size_t)s2 * 64 + lane];
        float2 v3 = g2[(size_t)s3 * 64 + lane];
        a0.x += v0.x; a0.y += v0.y;
        a1.x += v1.x; a1.y += v1.y;
        a2.x += v2.x; a2.y += v2.y;
        a3.x += v3.x; a3.y += v3.y;
    }
    for (; j < end; j++) {
        int s0 = csr_src[j];
        float2 v0 = g2[(size_t)s0 * 64 + lane];
        a0.x += v0.x; a0.y += v0.y;
    }

    float dv = dinv[node];
    float2 bv = ((const float2*)bias)[lane];
    float sx = a0.x + a1.x + a2.x + a3.x;
    float sy = a0.y + a1.y + a2.y + a3.y;
    float2 r;
    r.x = fmaxf(sx * dv + bv.x, 0.0f);
    r.y = fmaxf(sy * dv + bv.y, 0.0f);
    ((float2*)outb)[(size_t)node * 64 + lane] = r;
}

// ---- mean pool stage 1 ----
__global__ __launch_bounds__(256) void pool_kernel(const float* __restrict__ a,
                                                   float* __restrict__ pooled, int n) {
    int tid = blockIdx.x * 256 + threadIdx.x;  // 256 blocks -> 65536 threads
    int f = tid & 127;
    int i0 = tid >> 7;  // 0..511
    float s = 0.0f;
    for (int i = i0; i < n; i += 512) s += a[(size_t)i * FEAT + f];
    atomicAdd(&pooled[f], s);
}

// ---- final: out[c] = (pooled/N) . Wc[:,c] + bc[c] ----
__global__ __launch_bounds__(128) void final_kernel(const float* __restrict__ pooled,
                                                    const float* __restrict__ Wc,
                                                    const float* __restrict__ bc,
                                                    float* __restrict__ out,
                                                    int n, int C) {
    __shared__ float p[FEAT];
    int t = threadIdx.x;
    p[t] = pooled[t] * (1.0f / (float)n);
    __syncthreads();
    if (t < C) {
        float acc = bc[t];
        for (int h = 0; h < FEAT; h++)
            acc += p[h] * Wc[h * C + t];
        out[t] = acc;
    }
}

extern "C" void kernel_launch(void* const* d_in, const int* in_sizes, int n_in,
                              void* d_out, int out_size, void* d_ws, size_t ws_size,
                              hipStream_t stream) {
    const float* x  = (const float*)d_in[0];
    const int*   ei = (const int*)d_in[1];
    const float* W1 = (const float*)d_in[2];
    const float* b1 = (const float*)d_in[3];
    const float* W2 = (const float*)d_in[4];
    const float* b2 = (const float*)d_in[5];
    const float* Wc = (const float*)d_in[6];
    const float* bc = (const float*)d_in[7];

    const int N = in_sizes[0] / FEAT;      // 100000
    const int E = in_sizes[1] / 2;         // 1600000
    const int C = out_size;                // 32
    const int* srcI = ei;
    const int* dstI = ei + E;
    const int NB = (N + 1023) / 1024;      // scan blocks

    // workspace carve (256B aligned)
    auto align256 = [](size_t v) { return (v + 255) & ~(size_t)255; };
    char* w = (char*)d_ws;
    int*   cnt     = (int*)w;    w += align256((size_t)N * 4);
    float* dinv    = (float*)w;  w += align256((size_t)N * 4);
    int*   cursor  = (int*)w;    w += align256((size_t)N * 4);
    int*   csr_src = (int*)w;    w += align256((size_t)E * 4);
    int*   bsum    = (int*)w;    w += align256((size_t)NB * 4);
    int*   boff    = (int*)w;    w += align256((size_t)NB * 4);
    float* bufH    = (float*)w;  w += align256((size_t)N * FEAT * 4);
    float* bufA    = (float*)w;  w += align256((size_t)N * FEAT * 4);
    float* pooled  = (float*)w;  w += align256((size_t)FEAT * 4);

    hipMemsetAsync(cnt, 0, (size_t)N * 4, stream);
    hipMemsetAsync(pooled, 0, (size_t)FEAT * 4, stream);

    // degrees + dinv
    count_kernel<<<((E + 3) / 4 + 255) / 256, 256, 0, stream>>>(dstI, cnt, E);
    dinv_kernel<<<(N + 255) / 256, 256, 0, stream>>>(cnt, dinv, N);

    // CSR build (shared by both layers)
    scan_bsum<<<NB, 256, 0, stream>>>(cnt, bsum, N);
    scan_boff<<<1, 1, 0, stream>>>(bsum, boff, NB);
    scan_write<<<NB, 256, 0, stream>>>(cnt, boff, cursor, N);
    csr_scatter<<<(E + 255) / 256, 256, 0, stream>>>(srcI, dstI, cursor, csr_src, E);

    const int gAgg = (N + 3) / 4;
    const int gGemm = (N + 127) / 128;

    // ---- layer 1 ----
    gemm_node<<<gGemm, 256, 0, stream>>>(x, W1, dinv, bufH, N);
    agg_csr<<<gAgg, 256, 0, stream>>>(cursor, cnt, csr_src, bufH, dinv, b1, bufA, N);

    // ---- layer 2 ----
    gemm_node<<<gGemm, 256, 0, stream>>>(bufA, W2, dinv, bufH, N);
    agg_csr<<<gAgg, 256, 0, stream>>>(cursor, cnt, csr_src, bufH, dinv, b2, bufA, N);

    // ---- pool + classifier ----
    pool_kernel<<<256, 256, 0, stream>>>(bufA, pooled, N);
    final_kernel<<<1, 128, 0, stream>>>(pooled, Wc, bc, (float*)d_out, N, C);
}

// Round 5
// 586.985 us; speedup vs baseline: 9.9885x; 1.2313x over previous
//
#include <hip/hip_runtime.h>
#include <hip/hip_bf16.h>
#include <hip/hip_fp16.h>

// GCN: h1 = relu(Agg(x@W1)+b1); h2 = relu(Agg(h1@W2)+b2); out = mean(h2)@Wc + bc
// Agg via CSR gather (no fp32 atomics):
//   g = (X@W) * dinv[row]   (fused GEMM epilogue, stored fp16 to halve LLC gather BW)
//   out[d] = relu( dinv[d] * (g[d] + sum_{e: dst=d} g[src_e]) + b )
// CSR build is XCD-partitioned: block b handles dst-range (b&7) so each XCD's L2
// owns a contiguous slice of cnt/cursor/csr_src (no cross-XCD line bouncing).

#define FEAT 128
#define CHUNK 16384   // edges per chunk (multiple of 4 for int4 alignment)

// ---- degree count, XCD-partitioned ----
__global__ __launch_bounds__(256) void count_xcd(const int* __restrict__ dst,
                                                 int* __restrict__ cnt, int nE,
                                                 float pscale) {
    int part  = blockIdx.x & 7;
    int chunk = blockIdx.x >> 3;
    int beg = chunk * CHUNK;
    int end = min(nE, beg + CHUNK);
    for (int e = beg + (int)threadIdx.x * 4; e < end; e += 1024) {
        if (e + 3 < end) {
            int4 d4 = *(const int4*)(dst + e);
            if ((int)(d4.x * pscale) == part) atomicAdd(&cnt[d4.x], 1);
            if ((int)(d4.y * pscale) == part) atomicAdd(&cnt[d4.y], 1);
            if ((int)(d4.z * pscale) == part) atomicAdd(&cnt[d4.z], 1);
            if ((int)(d4.w * pscale) == part) atomicAdd(&cnt[d4.w], 1);
        } else {
            for (int k = e; k < end; k++) {
                int d = dst[k];
                if ((int)(d * pscale) == part) atomicAdd(&cnt[d], 1);
            }
        }
    }
}

// ---- dinv[i] = rsqrt(cnt[i] + 1)  (+1 = self loop) ----
__global__ __launch_bounds__(256) void dinv_kernel(const int* __restrict__ cnt,
                                                   float* __restrict__ dinv, int n) {
    int i = blockIdx.x * 256 + threadIdx.x;
    if (i < n) dinv[i] = rsqrtf((float)(cnt[i] + 1));
}

// ---- scan K1: per-block (1024 elems) sums ----
__global__ __launch_bounds__(256) void scan_bsum(const int* __restrict__ cnt,
                                                 int* __restrict__ bsum, int n) {
    __shared__ int red[256];
    int b = blockIdx.x, t = threadIdx.x;
    int base = b * 1024 + t * 4;
    int s = 0;
#pragma unroll
    for (int k = 0; k < 4; k++) {
        int i = base + k;
        if (i < n) s += cnt[i];
    }
    red[t] = s;
    __syncthreads();
    for (int off = 128; off > 0; off >>= 1) {
        if (t < off) red[t] += red[t + off];
        __syncthreads();
    }
    if (t == 0) bsum[b] = red[0];
}

// ---- scan K2: exclusive scan of block sums (single thread; nb ~ 98) ----
__global__ void scan_boff(const int* __restrict__ bsum, int* __restrict__ boff, int nb) {
    int run = 0;
    for (int i = 0; i < nb; i++) { boff[i] = run; run += bsum[i]; }
}

// ---- scan K3: per-block exclusive scan -> cursor[i] = global exclusive prefix ----
__global__ __launch_bounds__(256) void scan_write(const int* __restrict__ cnt,
                                                  const int* __restrict__ boff,
                                                  int* __restrict__ cursor, int n) {
    __shared__ int sc[256];
    int b = blockIdx.x, t = threadIdx.x;
    int base = b * 1024 + t * 4;
    int v[4];
    int s = 0;
#pragma unroll
    for (int k = 0; k < 4; k++) {
        int i = base + k;
        v[k] = (i < n) ? cnt[i] : 0;
        s += v[k];
    }
    sc[t] = s;
    __syncthreads();
    for (int off = 1; off < 256; off <<= 1) {
        int add = (t >= off) ? sc[t - off] : 0;
        __syncthreads();
        sc[t] += add;
        __syncthreads();
    }
    int excl = boff[b] + sc[t] - s;
#pragma unroll
    for (int k = 0; k < 4; k++) {
        int i = base + k;
        if (i < n) cursor[i] = excl;
        excl += v[k];
    }
}

// ---- scatter edges into CSR buckets, XCD-partitioned ----
__global__ __launch_bounds__(256) void csr_scatter_xcd(const int* __restrict__ src,
                                                       const int* __restrict__ dst,
                                                       int* __restrict__ cursor,
                                                       int* __restrict__ csr_src,
                                                       int nE, float pscale) {
    int part  = blockIdx.x & 7;
    int chunk = blockIdx.x >> 3;
    int beg = chunk * CHUNK;
    int end = min(nE, beg + CHUNK);
    for (int e = beg + (int)threadIdx.x * 4; e < end; e += 1024) {
        if (e + 3 < end) {
            int4 d4 = *(const int4*)(dst + e);
            if ((int)(d4.x * pscale) == part) {
                int pos = atomicAdd(&cursor[d4.x], 1);
                csr_src[pos] = src[e + 0];
            }
            if ((int)(d4.y * pscale) == part) {
                int pos = atomicAdd(&cursor[d4.y], 1);
                csr_src[pos] = src[e + 1];
            }
            if ((int)(d4.z * pscale) == part) {
                int pos = atomicAdd(&cursor[d4.z], 1);
                csr_src[pos] = src[e + 2];
            }
            if ((int)(d4.w * pscale) == part) {
                int pos = atomicAdd(&cursor[d4.w], 1);
                csr_src[pos] = src[e + 3];
            }
        } else {
            for (int k = e; k < end; k++) {
                int d = dst[k];
                if ((int)(d * pscale) == part) {
                    int pos = atomicAdd(&cursor[d], 1);
                    csr_src[pos] = src[k];
                }
            }
        }
    }
}

// ---- GEMM: gout[N][128] = fp16( (X@W) * dinv[row] ); 4 rows x 16 cols/thread ----
__global__ __launch_bounds__(256) void gemm_node(const float* __restrict__ X,
                                                 const float* __restrict__ W,
                                                 const float* __restrict__ dinv,
                                                 __half* __restrict__ gout, int n) {
    __shared__ float Ws[FEAT * FEAT];
    for (int i = threadIdx.x; i < FEAT * FEAT / 4; i += 256)
        ((float4*)Ws)[i] = ((const float4*)W)[i];
    __syncthreads();

    int cg = threadIdx.x & 7;        // col group -> 16 cols
    int rs = threadIdx.x >> 3;       // row slot 0..31 -> 4 rows each
    int cb = cg * 16;
    int r0 = blockIdx.x * 128 + rs * 4;
    if (r0 >= n) return;
    bool full = (r0 + 3 < n);

    float acc[4][16];
#pragma unroll
    for (int rr = 0; rr < 4; rr++)
#pragma unroll
        for (int j = 0; j < 16; j++) acc[rr][j] = 0.0f;

    const float* x0 = X + (size_t)r0 * FEAT;

    for (int k = 0; k < FEAT; k += 4) {
        float4 a[4];
        if (full) {
#pragma unroll
            for (int rr = 0; rr < 4; rr++)
                a[rr] = *(const float4*)(x0 + (size_t)rr * FEAT + k);
        } else {
#pragma unroll
            for (int rr = 0; rr < 4; rr++)
                a[rr] = (r0 + rr < n) ? *(const float4*)(x0 + (size_t)rr * FEAT + k)
                                      : make_float4(0.f, 0.f, 0.f, 0.f);
        }
#pragma unroll
        for (int kk = 0; kk < 4; kk++) {
            const float* wr = &Ws[(k + kk) * FEAT + cb];
            float4 w0 = *(const float4*)(wr + 0);
            float4 w1 = *(const float4*)(wr + 4);
            float4 w2 = *(const float4*)(wr + 8);
            float4 w3 = *(const float4*)(wr + 12);
#pragma unroll
            for (int rr = 0; rr < 4; rr++) {
                float av = (&a[rr].x)[kk];
                acc[rr][0]  += av * w0.x; acc[rr][1]  += av * w0.y;
                acc[rr][2]  += av * w0.z; acc[rr][3]  += av * w0.w;
                acc[rr][4]  += av * w1.x; acc[rr][5]  += av * w1.y;
                acc[rr][6]  += av * w1.z; acc[rr][7]  += av * w1.w;
                acc[rr][8]  += av * w2.x; acc[rr][9]  += av * w2.y;
                acc[rr][10] += av * w2.z; acc[rr][11] += av * w2.w;
                acc[rr][12] += av * w3.x; acc[rr][13] += av * w3.y;
                acc[rr][14] += av * w3.z; acc[rr][15] += av * w3.w;
            }
        }
    }

#pragma unroll
    for (int rr = 0; rr < 4; rr++) {
        int r = r0 + rr;
        if (r >= n) break;
        float dv = dinv[r];
        alignas(16) __half2 tmp[8];
#pragma unroll
        for (int j = 0; j < 16; j += 2)
            tmp[j >> 1] = __float22half2_rn(
                make_float2(acc[rr][j] * dv, acc[rr][j + 1] * dv));
        __half* o = gout + (size_t)r * FEAT + cb;
        *(int4*)(o + 0) = *(int4*)(&tmp[0]);
        *(int4*)(o + 8) = *(int4*)(&tmp[4]);
    }
}

// ---- fused CSR aggregate + bias + relu. One wave per node, half2 per lane ----
__global__ __launch_bounds__(256) void agg_csr(const int* __restrict__ cursor,
                                               const int* __restrict__ cnt,
                                               const int* __restrict__ csr_src,
                                               const __half2* __restrict__ g2,
                                               const float* __restrict__ dinv,
                                               const float* __restrict__ bias,
                                               float* __restrict__ outb, int n) {
    int node = blockIdx.x * 4 + (threadIdx.x >> 6);
    if (node >= n) return;
    int lane = threadIdx.x & 63;

    int num = cnt[node];
    int end = cursor[node];       // after scatter, cursor = bucket end
    int beg = end - num;

    float2 a0 = __half22float2(g2[(size_t)node * 64 + lane]);  // self-loop term
    float2 a1 = make_float2(0.f, 0.f);
    float2 a2 = make_float2(0.f, 0.f);
    float2 a3 = make_float2(0.f, 0.f);

    int j = beg;
    for (; j + 7 < end; j += 8) {
        int s0 = csr_src[j + 0];
        int s1 = csr_src[j + 1];
        int s2 = csr_src[j + 2];
        int s3 = csr_src[j + 3];
        int s4 = csr_src[j + 4];
        int s5 = csr_src[j + 5];
        int s6 = csr_src[j + 6];
        int s7 = csr_src[j + 7];
        __half2 h0 = g2[(size_t)s0 * 64 + lane];
        __half2 h1 = g2[(size_t)s1 * 64 + lane];
        __half2 h2 = g2[(size_t)s2 * 64 + lane];
        __half2 h3 = g2[(size_t)s3 * 64 + lane];
        __half2 h4 = g2[(size_t)s4 * 64 + lane];
        __half2 h5 = g2[(size_t)s5 * 64 + lane];
        __half2 h6 = g2[(size_t)s6 * 64 + lane];
        __half2 h7 = g2[(size_t)s7 * 64 + lane];
        float2 v0 = __half22float2(h0);
        float2 v1 = __half22float2(h1);
        float2 v2 = __half22float2(h2);
        float2 v3 = __half22float2(h3);
        float2 v4 = __half22float2(h4);
        float2 v5 = __half22float2(h5);
        float2 v6 = __half22float2(h6);
        float2 v7 = __half22float2(h7);
        a0.x += v0.x; a0.y += v0.y;
        a1.x += v1.x; a1.y += v1.y;
        a2.x += v2.x; a2.y += v2.y;
        a3.x += v3.x; a3.y += v3.y;
        a0.x += v4.x; a0.y += v4.y;
        a1.x += v5.x; a1.y += v5.y;
        a2.x += v6.x; a2.y += v6.y;
        a3.x += v7.x; a3.y += v7.y;
    }
    for (; j < end; j++) {
        float2 v0 = __half22float2(g2[(size_t)csr_src[j] * 64 + lane]);
        a0.x += v0.x; a0.y += v0.y;
    }

    float dv = dinv[node];
    float2 bv = ((const float2*)bias)[lane];
    float sx = a0.x + a1.x + a2.x + a3.x;
    float sy = a0.y + a1.y + a2.y + a3.y;
    float2 r;
    r.x = fmaxf(sx * dv + bv.x, 0.0f);
    r.y = fmaxf(sy * dv + bv.y, 0.0f);
    ((float2*)outb)[(size_t)node * 64 + lane] = r;
}

// ---- mean pool stage 1 ----
__global__ __launch_bounds__(256) void pool_kernel(const float* __restrict__ a,
                                                   float* __restrict__ pooled, int n) {
    int tid = blockIdx.x * 256 + threadIdx.x;  // 256 blocks -> 65536 threads
    int f = tid & 127;
    int i0 = tid >> 7;  // 0..511
    float s = 0.0f;
    for (int i = i0; i < n; i += 512) s += a[(size_t)i * FEAT + f];
    atomicAdd(&pooled[f], s);
}

// ---- final: out[c] = (pooled/N) . Wc[:,c] + bc[c] ----
__global__ __launch_bounds__(128) void final_kernel(const float* __restrict__ pooled,
                                                    const float* __restrict__ Wc,
                                                    const float* __restrict__ bc,
                                                    float* __restrict__ out,
                                                    int n, int C) {
    __shared__ float p[FEAT];
    int t = threadIdx.x;
    p[t] = pooled[t] * (1.0f / (float)n);
    __syncthreads();
    if (t < C) {
        float acc = bc[t];
        for (int h = 0; h < FEAT; h++)
            acc += p[h] * Wc[h * C + t];
        out[t] = acc;
    }
}

extern "C" void kernel_launch(void* const* d_in, const int* in_sizes, int n_in,
                              void* d_out, int out_size, void* d_ws, size_t ws_size,
                              hipStream_t stream) {
    const float* x  = (const float*)d_in[0];
    const int*   ei = (const int*)d_in[1];
    const float* W1 = (const float*)d_in[2];
    const float* b1 = (const float*)d_in[3];
    const float* W2 = (const float*)d_in[4];
    const float* b2 = (const float*)d_in[5];
    const float* Wc = (const float*)d_in[6];
    const float* bc = (const float*)d_in[7];

    const int N = in_sizes[0] / FEAT;      // 100000
    const int E = in_sizes[1] / 2;         // 1600000
    const int C = out_size;                // 32
    const int* srcI = ei;
    const int* dstI = ei + E;
    const int NB = (N + 1023) / 1024;      // scan blocks
    const int NC = (E + CHUNK - 1) / CHUNK;
    const float pscale = 8.0f / (float)N;  // dst -> partition in [0,8)

    // workspace carve (256B aligned)
    auto align256 = [](size_t v) { return (v + 255) & ~(size_t)255; };
    char* w = (char*)d_ws;
    int*    cnt     = (int*)w;     w += align256((size_t)N * 4);
    float*  dinv    = (float*)w;   w += align256((size_t)N * 4);
    int*    cursor  = (int*)w;     w += align256((size_t)N * 4);
    int*    csr_src = (int*)w;     w += align256((size_t)E * 4);
    int*    bsum    = (int*)w;     w += align256((size_t)NB * 4);
    int*    boff    = (int*)w;     w += align256((size_t)NB * 4);
    __half* gbuf    = (__half*)w;  w += align256((size_t)N * FEAT * 2);
    float*  bufA    = (float*)w;   w += align256((size_t)N * FEAT * 4);
    float*  pooled  = (float*)w;   w += align256((size_t)FEAT * 4);

    hipMemsetAsync(cnt, 0, (size_t)N * 4, stream);
    hipMemsetAsync(pooled, 0, (size_t)FEAT * 4, stream);

    // degrees + dinv (XCD-partitioned count)
    count_xcd<<<NC * 8, 256, 0, stream>>>(dstI, cnt, E, pscale);
    dinv_kernel<<<(N + 255) / 256, 256, 0, stream>>>(cnt, dinv, N);

    // CSR build (shared by both layers)
    scan_bsum<<<NB, 256, 0, stream>>>(cnt, bsum, N);
    scan_boff<<<1, 1, 0, stream>>>(bsum, boff, NB);
    scan_write<<<NB, 256, 0, stream>>>(cnt, boff, cursor, N);
    csr_scatter_xcd<<<NC * 8, 256, 0, stream>>>(srcI, dstI, cursor, csr_src, E, pscale);

    const int gAgg = (N + 3) / 4;
    const int gGemm = (N + 127) / 128;

    // ---- layer 1 ----
    gemm_node<<<gGemm, 256, 0, stream>>>(x, W1, dinv, gbuf, N);
    agg_csr<<<gAgg, 256, 0, stream>>>(cursor, cnt, csr_src, (const __half2*)gbuf,
                                      dinv, b1, bufA, N);

    // ---- layer 2 ----
    gemm_node<<<gGemm, 256, 0, stream>>>(bufA, W2, dinv, gbuf, N);
    agg_csr<<<gAgg, 256, 0, stream>>>(cursor, cnt, csr_src, (const __half2*)gbuf,
                                      dinv, b2, bufA, N);

    // ---- pool + classifier ----
    pool_kernel<<<256, 256, 0, stream>>>(bufA, pooled, N);
    final_kernel<<<1, 128, 0, stream>>>(pooled, Wc, bc, (float*)d_out, N, C);
}

// Round 6
// 509.565 us; speedup vs baseline: 11.5060x; 1.1519x over previous
//
#include <hip/hip_runtime.h>
#include <hip/hip_bf16.h>

// GCN: h1 = relu(Agg(x@W1)+b1); h2 = relu(Agg(h1@W2)+b2); out = mean(h2)@Wc + bc
// Agg via CSR gather (no fp32 atomics), CSR build XCD-partitioned.
// GEMMs use mfma_f32_16x16x32_bf16, LDS-free:
//   - W pre-packed to k-block layout Wbf[(kb*128+n)*8+j] = bf16(W[kb*8+j][n])
//     so b_frags are coalesced 16B/lane global loads (L2-resident).
//   - A fragments load 16B/lane straight from row-major global (fp32->bf16
//     converted in-register for layer 1; layer 2 activations stored bf16).
// Verified MFMA maps: A[m=lane&15][k=quad*8+j]; B[k=quad*8+j][n=lane&15];
//                     D[row=quad*4+reg][col=lane&15].

#define FEAT 128
#define CHUNK 16384   // edges per chunk (multiple of 4 for int4 alignment)

typedef __attribute__((ext_vector_type(8))) short short8;
typedef __attribute__((ext_vector_type(4))) float float4v;

union I4S8 { int4 i; short8 s; };

static __device__ inline unsigned short f2bf(float f) {
    union { __hip_bfloat16 h; unsigned short u; } cv;
    cv.h = __float2bfloat16(f);
    return cv.u;
}

// ---- degree count, XCD-partitioned ----
__global__ __launch_bounds__(256) void count_xcd(const int* __restrict__ dst,
                                                 int* __restrict__ cnt, int nE,
                                                 float pscale) {
    int part  = blockIdx.x & 7;
    int chunk = blockIdx.x >> 3;
    int beg = chunk * CHUNK;
    int end = min(nE, beg + CHUNK);
    for (int e = beg + (int)threadIdx.x * 4; e < end; e += 1024) {
        if (e + 3 < end) {
            int4 d4 = *(const int4*)(dst + e);
            if ((int)(d4.x * pscale) == part) atomicAdd(&cnt[d4.x], 1);
            if ((int)(d4.y * pscale) == part) atomicAdd(&cnt[d4.y], 1);
            if ((int)(d4.z * pscale) == part) atomicAdd(&cnt[d4.z], 1);
            if ((int)(d4.w * pscale) == part) atomicAdd(&cnt[d4.w], 1);
        } else {
            for (int k = e; k < end; k++) {
                int d = dst[k];
                if ((int)(d * pscale) == part) atomicAdd(&cnt[d], 1);
            }
        }
    }
}

// ---- scan K1: per-block (1024 elems) sums ----
__global__ __launch_bounds__(256) void scan_bsum(const int* __restrict__ cnt,
                                                 int* __restrict__ bsum, int n) {
    __shared__ int red[256];
    int b = blockIdx.x, t = threadIdx.x;
    int base = b * 1024 + t * 4;
    int s = 0;
#pragma unroll
    for (int k = 0; k < 4; k++) {
        int i = base + k;
        if (i < n) s += cnt[i];
    }
    red[t] = s;
    __syncthreads();
    for (int off = 128; off > 0; off >>= 1) {
        if (t < off) red[t] += red[t + off];
        __syncthreads();
    }
    if (t == 0) bsum[b] = red[0];
}

// ---- scan K2: exclusive scan of block sums (single thread; nb ~ 98) ----
__global__ void scan_boff(const int* __restrict__ bsum, int* __restrict__ boff, int nb) {
    int run = 0;
    for (int i = 0; i < nb; i++) { boff[i] = run; run += bsum[i]; }
}

// ---- scan K3: cursor[i] = global exclusive prefix; also dinv = rsqrt(cnt+1) ----
__global__ __launch_bounds__(256) void scan_write(const int* __restrict__ cnt,
                                                  const int* __restrict__ boff,
                                                  int* __restrict__ cursor,
                                                  float* __restrict__ dinv, int n) {
    __shared__ int sc[256];
    int b = blockIdx.x, t = threadIdx.x;
    int base = b * 1024 + t * 4;
    int v[4];
    int s = 0;
#pragma unroll
    for (int k = 0; k < 4; k++) {
        int i = base + k;
        v[k] = (i < n) ? cnt[i] : 0;
        s += v[k];
    }
    sc[t] = s;
    __syncthreads();
    for (int off = 1; off < 256; off <<= 1) {
        int add = (t >= off) ? sc[t - off] : 0;
        __syncthreads();
        sc[t] += add;
        __syncthreads();
    }
    int excl = boff[b] + sc[t] - s;
#pragma unroll
    for (int k = 0; k < 4; k++) {
        int i = base + k;
        if (i < n) {
            cursor[i] = excl;
            dinv[i] = rsqrtf((float)(v[k] + 1));
        }
        excl += v[k];
    }
}

// ---- scatter edges into CSR buckets, XCD-partitioned ----
__global__ __launch_bounds__(256) void csr_scatter_xcd(const int* __restrict__ src,
                                                       const int* __restrict__ dst,
                                                       int* __restrict__ cursor,
                                                       int* __restrict__ csr_src,
                                                       int nE, float pscale) {
    int part  = blockIdx.x & 7;
    int chunk = blockIdx.x >> 3;
    int beg = chunk * CHUNK;
    int end = min(nE, beg + CHUNK);
    for (int e = beg + (int)threadIdx.x * 4; e < end; e += 1024) {
        if (e + 3 < end) {
            int4 d4 = *(const int4*)(dst + e);
            if ((int)(d4.x * pscale) == part) {
                int pos = atomicAdd(&cursor[d4.x], 1);
                csr_src[pos] = src[e + 0];
            }
            if ((int)(d4.y * pscale) == part) {
                int pos = atomicAdd(&cursor[d4.y], 1);
                csr_src[pos] = src[e + 1];
            }
            if ((int)(d4.z * pscale) == part) {
                int pos = atomicAdd(&cursor[d4.z], 1);
                csr_src[pos] = src[e + 2];
            }
            if ((int)(d4.w * pscale) == part) {
                int pos = atomicAdd(&cursor[d4.w], 1);
                csr_src[pos] = src[e + 3];
            }
        } else {
            for (int k = e; k < end; k++) {
                int d = dst[k];
                if ((int)(d * pscale) == part) {
                    int pos = atomicAdd(&cursor[d], 1);
                    csr_src[pos] = src[k];
                }
            }
        }
    }
}

// ---- W pre-pack: Wbf[(kb*128+n)*8+j] = bf16(W[(kb*8+j)*128+n]) ----
__global__ __launch_bounds__(256) void wprep(const float* __restrict__ W,
                                             unsigned short* __restrict__ Wbf) {
    int tid = blockIdx.x * 256 + threadIdx.x;   // 16384 threads
    int chunk = tid >> 3, j = tid & 7;
    int kb = chunk >> 7, nn = chunk & 127;
    Wbf[tid] = f2bf(W[(kb * 8 + j) * FEAT + nn]);
}

// ---- MFMA GEMM: gout[N][128](bf16) = bf16(X) @ Wbf * dinv[row] ----
// Block = 4 waves, wave = 16 rows x 128 cols. AFP32: A is fp32 (layer 1).
template <bool AFP32>
__global__ __launch_bounds__(256) void gemm_mfma(const void* __restrict__ Xv,
                                                 const unsigned short* __restrict__ Wbf,
                                                 const float* __restrict__ dinv,
                                                 unsigned short* __restrict__ gout,
                                                 int n) {
    int wave = threadIdx.x >> 6, lane = threadIdx.x & 63;
    int m0 = blockIdx.x * 64 + wave * 16;
    if (m0 >= n) return;
    int col = lane & 15, quad = lane >> 4;
    int mc = min(m0 + col, n - 1);

    // A fragments: afr[ks] = A[m][ks*32 + quad*8 .. +7]
    short8 afr[4];
    if (AFP32) {
        const float* X = (const float*)Xv;
        const float* xr = X + (size_t)mc * FEAT + quad * 8;
#pragma unroll
        for (int ks = 0; ks < 4; ks++) {
            float4 lo = *(const float4*)(xr + ks * 32);
            float4 hi = *(const float4*)(xr + ks * 32 + 4);
            short8 a;
            a[0] = (short)f2bf(lo.x); a[1] = (short)f2bf(lo.y);
            a[2] = (short)f2bf(lo.z); a[3] = (short)f2bf(lo.w);
            a[4] = (short)f2bf(hi.x); a[5] = (short)f2bf(hi.y);
            a[6] = (short)f2bf(hi.z); a[7] = (short)f2bf(hi.w);
            afr[ks] = a;
        }
    } else {
        const int4* X = (const int4*)Xv;           // 8 bf16 per int4
        const int4* xr = X + (size_t)mc * (FEAT / 8) + quad;
#pragma unroll
        for (int ks = 0; ks < 4; ks++) {
            I4S8 u; u.i = xr[ks * 4];
            afr[ks] = u.s;
        }
    }

    float dvr[4];
#pragma unroll
    for (int r = 0; r < 4; r++)
        dvr[r] = dinv[min(m0 + quad * 4 + r, n - 1)];

    const int4* Wb = (const int4*)Wbf;             // one int4 = one 8-elem chunk
#pragma unroll
    for (int nt = 0; nt < 8; nt++) {
        float4v acc = {0.f, 0.f, 0.f, 0.f};
#pragma unroll
        for (int ks = 0; ks < 4; ks++) {
            int kb = ks * 4 + quad;
            I4S8 u; u.i = Wb[kb * FEAT + nt * 16 + col];
            acc = __builtin_amdgcn_mfma_f32_16x16x32_bf16(afr[ks], u.s, acc, 0, 0, 0);
        }
#pragma unroll
        for (int r = 0; r < 4; r++) {
            int row = m0 + quad * 4 + r;
            if (row < n)
                gout[(size_t)row * FEAT + nt * 16 + col] = f2bf(acc[r] * dvr[r]);
        }
    }
}

// ---- fused CSR aggregate + bias + relu. One wave per node, bf162 per lane ----
__global__ __launch_bounds__(256) void agg_csr(const int* __restrict__ cursor,
                                               const int* __restrict__ cnt,
                                               const int* __restrict__ csr_src,
                                               const __hip_bfloat162* __restrict__ g2,
                                               const float* __restrict__ dinv,
                                               const float* __restrict__ bias,
                                               __hip_bfloat162* __restrict__ outb,
                                               int n) {
    int node = blockIdx.x * 4 + (threadIdx.x >> 6);
    if (node >= n) return;
    int lane = threadIdx.x & 63;

    int num = cnt[node];
    int end = cursor[node];       // after scatter, cursor = bucket end
    int beg = end - num;

    float2 a0 = __bfloat1622float2(g2[(size_t)node * 64 + lane]);  // self-loop
    float2 a1 = make_float2(0.f, 0.f);
    float2 a2 = make_float2(0.f, 0.f);
    float2 a3 = make_float2(0.f, 0.f);

    int j = beg;
    for (; j + 7 < end; j += 8) {
        int s0 = csr_src[j + 0];
        int s1 = csr_src[j + 1];
        int s2 = csr_src[j + 2];
        int s3 = csr_src[j + 3];
        int s4 = csr_src[j + 4];
        int s5 = csr_src[j + 5];
        int s6 = csr_src[j + 6];
        int s7 = csr_src[j + 7];
        __hip_bfloat162 h0 = g2[(size_t)s0 * 64 + lane];
        __hip_bfloat162 h1 = g2[(size_t)s1 * 64 + lane];
        __hip_bfloat162 h2 = g2[(size_t)s2 * 64 + lane];
        __hip_bfloat162 h3 = g2[(size_t)s3 * 64 + lane];
        __hip_bfloat162 h4 = g2[(size_t)s4 * 64 + lane];
        __hip_bfloat162 h5 = g2[(size_t)s5 * 64 + lane];
        __hip_bfloat162 h6 = g2[(size_t)s6 * 64 + lane];
        __hip_bfloat162 h7 = g2[(size_t)s7 * 64 + lane];
        float2 v0 = __bfloat1622float2(h0);
        float2 v1 = __bfloat1622float2(h1);
        float2 v2 = __bfloat1622float2(h2);
        float2 v3 = __bfloat1622float2(h3);
        float2 v4 = __bfloat1622float2(h4);
        float2 v5 = __bfloat1622float2(h5);
        float2 v6 = __bfloat1622float2(h6);
        float2 v7 = __bfloat1622float2(h7);
        a0.x += v0.x; a0.y += v0.y;
        a1.x += v1.x; a1.y += v1.y;
        a2.x += v2.x; a2.y += v2.y;
        a3.x += v3.x; a3.y += v3.y;
        a0.x += v4.x; a0.y += v4.y;
        a1.x += v5.x; a1.y += v5.y;
        a2.x += v6.x; a2.y += v6.y;
        a3.x += v7.x; a3.y += v7.y;
    }
    for (; j < end; j++) {
        float2 v0 = __bfloat1622float2(g2[(size_t)csr_src[j] * 64 + lane]);
        a0.x += v0.x; a0.y += v0.y;
    }

    float dv = dinv[node];
    float2 bv = ((const float2*)bias)[lane];
    float sx = a0.x + a1.x + a2.x + a3.x;
    float sy = a0.y + a1.y + a2.y + a3.y;
    float2 r;
    r.x = fmaxf(sx * dv + bv.x, 0.0f);
    r.y = fmaxf(sy * dv + bv.y, 0.0f);
    outb[(size_t)node * 64 + lane] = __float22bfloat162_rn(r);
}

// ---- mean pool stage 1 (bf16 input) ----
__global__ __launch_bounds__(256) void pool_kernel(const __hip_bfloat16* __restrict__ a,
                                                   float* __restrict__ pooled, int n) {
    int tid = blockIdx.x * 256 + threadIdx.x;  // 256 blocks -> 65536 threads
    int f = tid & 127;
    int i0 = tid >> 7;  // 0..511
    float s = 0.0f;
    for (int i = i0; i < n; i += 512) s += __bfloat162float(a[(size_t)i * FEAT + f]);
    atomicAdd(&pooled[f], s);
}

// ---- final: out[c] = (pooled/N) . Wc[:,c] + bc[c] ----
__global__ __launch_bounds__(128) void final_kernel(const float* __restrict__ pooled,
                                                    const float* __restrict__ Wc,
                                                    const float* __restrict__ bc,
                                                    float* __restrict__ out,
                                                    int n, int C) {
    __shared__ float p[FEAT];
    int t = threadIdx.x;
    p[t] = pooled[t] * (1.0f / (float)n);
    __syncthreads();
    if (t < C) {
        float acc = bc[t];
        for (int h = 0; h < FEAT; h++)
            acc += p[h] * Wc[h * C + t];
        out[t] = acc;
    }
}

extern "C" void kernel_launch(void* const* d_in, const int* in_sizes, int n_in,
                              void* d_out, int out_size, void* d_ws, size_t ws_size,
                              hipStream_t stream) {
    const float* x  = (const float*)d_in[0];
    const int*   ei = (const int*)d_in[1];
    const float* W1 = (const float*)d_in[2];
    const float* b1 = (const float*)d_in[3];
    const float* W2 = (const float*)d_in[4];
    const float* b2 = (const float*)d_in[5];
    const float* Wc = (const float*)d_in[6];
    const float* bc = (const float*)d_in[7];

    const int N = in_sizes[0] / FEAT;      // 100000
    const int E = in_sizes[1] / 2;         // 1600000
    const int C = out_size;                // 32
    const int* srcI = ei;
    const int* dstI = ei + E;
    const int NB = (N + 1023) / 1024;      // scan blocks
    const int NC = (E + CHUNK - 1) / CHUNK;
    const float pscale = 8.0f / (float)N;  // dst -> partition in [0,8)

    // workspace carve (256B aligned)
    auto align256 = [](size_t v) { return (v + 255) & ~(size_t)255; };
    char* w = (char*)d_ws;
    int*            cnt     = (int*)w;            w += align256((size_t)N * 4);
    float*          dinv    = (float*)w;          w += align256((size_t)N * 4);
    int*            cursor  = (int*)w;            w += align256((size_t)N * 4);
    int*            csr_src = (int*)w;            w += align256((size_t)E * 4);
    int*            bsum    = (int*)w;            w += align256((size_t)NB * 4);
    int*            boff    = (int*)w;            w += align256((size_t)NB * 4);
    unsigned short* Wbf1    = (unsigned short*)w; w += align256((size_t)FEAT * FEAT * 2);
    unsigned short* Wbf2    = (unsigned short*)w; w += align256((size_t)FEAT * FEAT * 2);
    unsigned short* gbuf    = (unsigned short*)w; w += align256((size_t)N * FEAT * 2);
    unsigned short* bufA    = (unsigned short*)w; w += align256((size_t)N * FEAT * 2);
    float*          pooled  = (float*)w;          w += align256((size_t)FEAT * 4);

    hipMemsetAsync(cnt, 0, (size_t)N * 4, stream);
    hipMemsetAsync(pooled, 0, (size_t)FEAT * 4, stream);

    // W pre-pack (tiny)
    wprep<<<64, 256, 0, stream>>>(W1, Wbf1);
    wprep<<<64, 256, 0, stream>>>(W2, Wbf2);

    // degrees (XCD-partitioned count)
    count_xcd<<<NC * 8, 256, 0, stream>>>(dstI, cnt, E, pscale);

    // CSR build (shared by both layers); dinv fused into scan_write
    scan_bsum<<<NB, 256, 0, stream>>>(cnt, bsum, N);
    scan_boff<<<1, 1, 0, stream>>>(bsum, boff, NB);
    scan_write<<<NB, 256, 0, stream>>>(cnt, boff, cursor, dinv, N);
    csr_scatter_xcd<<<NC * 8, 256, 0, stream>>>(srcI, dstI, cursor, csr_src, E, pscale);

    const int gAgg = (N + 3) / 4;
    const int gGemm = (N + 63) / 64;

    // ---- layer 1 ----
    gemm_mfma<true><<<gGemm, 256, 0, stream>>>(x, Wbf1, dinv, gbuf, N);
    agg_csr<<<gAgg, 256, 0, stream>>>(cursor, cnt, csr_src,
                                      (const __hip_bfloat162*)gbuf, dinv, b1,
                                      (__hip_bfloat162*)bufA, N);

    // ---- layer 2 ----
    gemm_mfma<false><<<gGemm, 256, 0, stream>>>(bufA, Wbf2, dinv, gbuf, N);
    agg_csr<<<gAgg, 256, 0, stream>>>(cursor, cnt, csr_src,
                                      (const __hip_bfloat162*)gbuf, dinv, b2,
                                      (__hip_bfloat162*)bufA, N);

    // ---- pool + classifier ----
    pool_kernel<<<256, 256, 0, stream>>>((const __hip_bfloat16*)bufA, pooled, N);
    final_kernel<<<1, 128, 0, stream>>>(pooled, Wc, bc, (float*)d_out, N, C);
}